// Round 7
// baseline (323.633 us; speedup 1.0000x reference)
//
#include <hip/hip_runtime.h>
#include <hip/hip_bf16.h>

// Problem constants
#define BATCH   65536
#define HW      28
#define OHW     26
#define FEAT    676
#define HID     200
#define NCLS    10
#define MT2     64                  // images per gemm block (4 m-tiles)
#define GBLOCKS (BATCH / MT2)       // 1024
#define KC1     25                  // K-chunks for GEMM1: 784 -> 800 = 25*32

// LDS layout (shorts): A triple-buffer + B double-buffer, hidA overlaid.
#define ABUF    2048                // shorts per A buffer (4 KB)
#define BOFF    6144                // bBuf starts after 3 A buffers
#define BBUF    6656                // shorts per B buffer (13 KB: 13 tiles x 64 x 8)
#define SHTOT   19456               // 38,912 B total -> 4 blocks/CU

typedef __attribute__((ext_vector_type(8))) __bf16 bf16x8;
typedef __attribute__((ext_vector_type(4))) float  f32x4;

// Raw workgroup barrier WITHOUT __syncthreads()'s vmcnt(0) drain:
// lgkmcnt(0) makes this round's ds ops visible; global loads in flight
// (consumed later by ds_writes with compiler-counted vmcnt waits) are NOT
// drained — T3/T4: never vmcnt(0) in the main loop.
#define KBAR() asm volatile("s_waitcnt lgkmcnt(0)\n\ts_barrier" ::: "memory")

__device__ __forceinline__ unsigned int pk2(float a, float b) {
  __hip_bfloat16 ha = __float2bfloat16(a), hb = __float2bfloat16(b);
  return (unsigned int)__builtin_bit_cast(unsigned short, ha)
       | ((unsigned int)__builtin_bit_cast(unsigned short, hb) << 16);
}

// fslot: A-fragment layout with XOR swizzle, used ONLY for hidA.
__device__ __forceinline__ unsigned short* fslot(unsigned short* base, int m, int k) {
  const int kc = k >> 5;
  return base + ((kc * 64 + ((k >> 3) & 3) * 16 + (m ^ (kc & 7))) * 8) + (k & 7);
}

// ---------------------------------------------------------------------------
// prep_w1e: fold the 3x3 conv into w1 (feat = x * C^T  =>  x @ (C^T w1)).
// Output B-fragment order: chunk c = (kc*13+nt)*64 + lane holds j=0..7 of
// k=kc*32+(lane>>4)*8+j, n = nt*16+(lane&15)  (K pad 800, N pad 208).
// ---------------------------------------------------------------------------
__global__ __launch_bounds__(256) void prep_w1e(const float* __restrict__ w1,
                                                const float* __restrict__ cwp,
                                                unsigned short* __restrict__ w1e) {
  int c = blockIdx.x * 256 + threadIdx.x;
  if (c >= KC1 * 13 * 64) return;
  int lane = c & 63, g = c >> 6;
  int kc = g / 13, nt = g - kc * 13;
  int ln = lane & 15, qd = lane >> 4;
  int n = nt * 16 + ln;
  float cw[9];
  #pragma unroll
  for (int t = 0; t < 9; ++t) cw[t] = cwp[t];
  float v[8];
  #pragma unroll
  for (int j = 0; j < 8; ++j) {
    int k = kc * 32 + qd * 8 + j;
    float s = 0.f;
    if (k < 784 && n < HID) {
      int ri = k / 28, ci = k - ri * 28;
      #pragma unroll
      for (int di = 0; di < 3; ++di) {
        int r = ri - di;
        if (r >= 0 && r < OHW) {
          #pragma unroll
          for (int dj = 0; dj < 3; ++dj) {
            int cc = ci - dj;
            if (cc >= 0 && cc < OHW) s += cw[di * 3 + dj] * w1[(r * OHW + cc) * HID + n];
          }
        }
      }
    }
    v[j] = s;
  }
  uint4 o = make_uint4(pk2(v[0], v[1]), pk2(v[2], v[3]),
                       pk2(v[4], v[5]), pk2(v[6], v[7]));
  *(uint4*)(w1e + (size_t)c * 8) = o;
}

// w2 (200x10 f32) -> bf16 B-fragment order, K=224 N=16 padded. 7 KB.
__global__ __launch_bounds__(256) void prep_w2f(const float* __restrict__ w2,
                                                unsigned short* __restrict__ w2f) {
  int c = blockIdx.x * 256 + threadIdx.x;
  if (c >= 7 * 64) return;
  int lane = c & 63, kc = c >> 6;
  int col = lane & 15;
  float v[8];
  #pragma unroll
  for (int j = 0; j < 8; ++j) {
    int k = kc * 32 + (lane >> 4) * 8 + j;
    v[j] = (col < NCLS && k < HID) ? w2[k * NCLS + col] : 0.f;
  }
  uint4 o = make_uint4(pk2(v[0], v[1]), pk2(v[2], v[3]),
                       pk2(v[4], v[5]), pk2(v[6], v[7]));
  *(uint4*)(w2f + (size_t)c * 8) = o;
}

// ---------------------------------------------------------------------------
// fused7: MFMA operands come ONLY from LDS (lgkm waits); ALL global loads
// (B-stage from L2, x-stage from HBM) are consumed by late ds_writes with
// counted vmcnt waits and stay in flight across KBAR barriers.
//   iter kc: issue B(kc+1); issue x(kc+2); ds_read A(kc),B(kc); 16 MFMA;
//            cvt+write x(kc+2)->aBuf[(kc+2)%3]; write B(kc+1)->bBuf[(kc+1)&1];
//            KBAR.
// ---------------------------------------------------------------------------
template<int NT0, int NT>
__device__ __forceinline__ void gemm1_body(
    const float* __restrict__ x, const unsigned short* __restrict__ w1e,
    const float* __restrict__ b1, unsigned short* sh,
    int lane, int tid, int blk64) {
  const int ln = lane & 15, qd = lane >> 4;

  // x staging role: thread tid stages chunk tid (image blk64+(tid>>6)*16+(tid&15),
  // cols (tid>>4&3)*8 .. +7) — fully coalesced 32B/lane f32 reads.
  const int sc_qd = (tid >> 4) & 3;
  const float* xrow = x + ((size_t)blk64 + (tid >> 6) * 16 + (tid & 15)) * 784 + sc_qd * 8;
  // B staging role: thread tid stages chunks tid, tid+256, tid+512 (+768 if <832).
  const int t3ok = (tid + 768) < 832;

  f32x4 acc[4][NT];
  #pragma unroll
  for (int mi = 0; mi < 4; ++mi)
    #pragma unroll
    for (int t = 0; t < NT; ++t) acc[mi][t] = (f32x4){0.f, 0.f, 0.f, 0.f};

  // ---- prologue: stage x(0)->aBuf0, x(1)->aBuf1, B(0)->bBuf0
  {
    float4 f0 = *(const float4*)(xrow);
    float4 f1 = *(const float4*)(xrow + 4);
    float4 g0 = *(const float4*)(xrow + 32);
    float4 g1 = *(const float4*)(xrow + 36);
    *(uint4*)(sh + tid * 8) = make_uint4(pk2(f0.x, f0.y), pk2(f0.z, f0.w),
                                         pk2(f1.x, f1.y), pk2(f1.z, f1.w));
    *(uint4*)(sh + ABUF + tid * 8) = make_uint4(pk2(g0.x, g0.y), pk2(g0.z, g0.w),
                                                pk2(g1.x, g1.y), pk2(g1.z, g1.w));
    uint4 b0 = *(const uint4*)(w1e + (size_t)tid * 8);
    uint4 b1v = *(const uint4*)(w1e + (size_t)(tid + 256) * 8);
    uint4 b2v = *(const uint4*)(w1e + (size_t)(tid + 512) * 8);
    *(uint4*)(sh + BOFF + tid * 8) = b0;
    *(uint4*)(sh + BOFF + (tid + 256) * 8) = b1v;
    *(uint4*)(sh + BOFF + (tid + 512) * 8) = b2v;
    if (t3ok) {
      uint4 b3v = *(const uint4*)(w1e + (size_t)(tid + 768) * 8);
      *(uint4*)(sh + BOFF + (tid + 768) * 8) = b3v;
    }
  }
  __syncthreads();   // full drain once is fine

  for (int kc = 0; kc < KC1; ++kc) {
    // -- issue B(kc+1) stage loads (L2-resident w1e), oldest this iter
    uint4 bq0, bq1, bq2, bq3;
    const bool havB = (kc + 1 < KC1);
    if (havB) {
      const unsigned short* wsrc = w1e + (size_t)(kc + 1) * 832 * 8;
      bq0 = *(const uint4*)(wsrc + (size_t)tid * 8);
      bq1 = *(const uint4*)(wsrc + (size_t)(tid + 256) * 8);
      bq2 = *(const uint4*)(wsrc + (size_t)(tid + 512) * 8);
      if (t3ok) bq3 = *(const uint4*)(wsrc + (size_t)(tid + 768) * 8);
    }
    // -- issue x(kc+2) stage loads (HBM), newest this iter
    float4 fq0, fq1;
    const bool havA = (kc + 2 < KC1);
    const bool atail = (kc + 2 == KC1 - 1) && (sc_qd >= 2);   // k>=784 -> zeros
    if (havA && !atail) {
      fq0 = *(const float4*)(xrow + (kc + 2) * 32);
      fq1 = *(const float4*)(xrow + (kc + 2) * 32 + 4);
    }

    // -- compute on LDS-resident tiles (lgkm-only waits)
    const unsigned short* ab = sh + (kc % 3) * ABUF;
    const unsigned short* bb = sh + BOFF + (kc & 1) * BBUF;
    bf16x8 a[4];
    #pragma unroll
    for (int mi = 0; mi < 4; ++mi)
      a[mi] = *(const bf16x8*)(ab + mi * 512 + lane * 8);
    #pragma unroll
    for (int t = 0; t < NT; ++t) {
      bf16x8 b = *(const bf16x8*)(bb + ((NT0 + t) * 64 + lane) * 8);
      #pragma unroll
      for (int mi = 0; mi < 4; ++mi)
        acc[mi][t] = __builtin_amdgcn_mfma_f32_16x16x32_bf16(a[mi], b, acc[mi][t], 0, 0, 0);
    }

    // -- late writes: A first (x is older), then B
    if (havA) {
      uint4 cv;
      if (atail) cv = make_uint4(0u, 0u, 0u, 0u);
      else       cv = make_uint4(pk2(fq0.x, fq0.y), pk2(fq0.z, fq0.w),
                                 pk2(fq1.x, fq1.y), pk2(fq1.z, fq1.w));
      *(uint4*)(sh + ((kc + 2) % 3) * ABUF + tid * 8) = cv;
    }
    if (havB) {
      unsigned short* bdst = sh + BOFF + ((kc + 1) & 1) * BBUF;
      *(uint4*)(bdst + tid * 8) = bq0;
      *(uint4*)(bdst + (tid + 256) * 8) = bq1;
      *(uint4*)(bdst + (tid + 512) * 8) = bq2;
      if (t3ok) *(uint4*)(bdst + (tid + 768) * 8) = bq3;
    }
    KBAR();                       // lgkm-only; global loads stay in flight
  }

  __syncthreads();   // all LDS reads done -> safe to overlay hidA on sh

  // zero hid K-pad (k=200..223): 4 tiles x 16 rows x 12 dwords
  for (int i = tid; i < 768; i += 256) {
    int mi = i / 192, r = i - mi * 192, m = r / 12, d = r - m * 12;
    *(unsigned int*)fslot(sh + mi * 3584, m, 200 + 2 * d) = 0u;
  }

  // epilogue: relu(acc + b1) -> bf16 hidA (fslot layout per m-tile)
  #pragma unroll
  for (int t = 0; t < NT; ++t) {
    const int n = (NT0 + t) * 16 + ln;
    if (n < HID) {
      const float bias = b1[n];
      const int kc2 = n >> 5, qd2 = (n >> 3) & 3, j2 = n & 7, c2 = kc2 & 7;
      #pragma unroll
      for (int mi = 0; mi < 4; ++mi)
        #pragma unroll
        for (int rr = 0; rr < 4; ++rr) {
          const int m = qd * 4 + rr;
          float h = fmaxf(acc[mi][t][rr] + bias, 0.f);
          __hip_bfloat16 hb = __float2bfloat16(h);
          sh[mi * 3584 + (kc2 * 64 + qd2 * 16 + (m ^ c2)) * 8 + j2] =
              __builtin_bit_cast(unsigned short, hb);
        }
    }
  }
}

__global__ __launch_bounds__(256, 4) void fused7(
    const float* __restrict__ x, const unsigned short* __restrict__ w1e,
    const unsigned short* __restrict__ w2f, const float* __restrict__ b1,
    const float* __restrict__ b2, float* __restrict__ out) {
  __shared__ __align__(16) unsigned short sh[SHTOT];   // 38,912 B
  const int tid  = threadIdx.x;
  const int wave = tid >> 6;
  const int lane = tid & 63;
  const int blk64 = blockIdx.x * MT2;

  switch (wave) {
    case 0:  gemm1_body<0, 4>(x, w1e, b1, sh, lane, tid, blk64); break;
    case 1:  gemm1_body<4, 3>(x, w1e, b1, sh, lane, tid, blk64); break;
    case 2:  gemm1_body<7, 3>(x, w1e, b1, sh, lane, tid, blk64); break;
    default: gemm1_body<10, 3>(x, w1e, b1, sh, lane, tid, blk64); break;
  }
  __syncthreads();   // hidA complete (incl. pads)

  // GEMM2: wave w handles m-tile w. 7 MFMA over K=224.
  const int ln = lane & 15, qd = lane >> 4;
  f32x4 acc2 = (f32x4){0.f, 0.f, 0.f, 0.f};
  #pragma unroll
  for (int kc = 0; kc < 7; ++kc) {
    bf16x8 a = *(const bf16x8*)&sh[wave * 3584 + (kc * 64 + (lane ^ (kc & 7))) * 8];
    bf16x8 b = *(const bf16x8*)(w2f + ((size_t)kc * 64 + lane) * 8);
    acc2 = __builtin_amdgcn_mfma_f32_16x16x32_bf16(a, b, acc2, 0, 0, 0);
  }
  if (ln < NCLS) {
    const float bb = b2[ln];
    #pragma unroll
    for (int rr = 0; rr < 4; ++rr) {
      out[((size_t)(blockIdx.x * 4 + wave) * 16 + qd * 4 + rr) * NCLS + ln] = acc2[rr] + bb;
    }
  }
}

extern "C" void kernel_launch(void* const* d_in, const int* in_sizes, int n_in,
                              void* d_out, int out_size, void* d_ws, size_t ws_size,
                              hipStream_t stream) {
  const float* x  = (const float*)d_in[0];
  const float* cw = (const float*)d_in[1];
  const float* w1 = (const float*)d_in[2];
  const float* b1 = (const float*)d_in[3];
  const float* w2 = (const float*)d_in[4];
  const float* b2 = (const float*)d_in[5];
  float* out = (float*)d_out;

  unsigned short* w1e = (unsigned short*)d_ws;                      // 332,800 B
  unsigned short* w2f = (unsigned short*)((char*)d_ws + 335872);    //   7,168 B

  hipLaunchKernelGGL(prep_w1e, dim3((KC1 * 13 * 64 + 255) / 256), dim3(256), 0, stream,
                     w1, cw, w1e);
  hipLaunchKernelGGL(prep_w2f, dim3(2), dim3(256), 0, stream, w2, w2f);
  hipLaunchKernelGGL(fused7, dim3(GBLOCKS), dim3(256), 0, stream,
                     x, w1e, w2f, b1, b2, out);
}